// Round 11
// baseline (196.670 us; speedup 1.0000x reference)
//
#include <hip/hip_runtime.h>
#include <math.h>

#define B_  2
#define S_  2048
#define D_  1024
#define H_  16
#define HD_ 64
#define BS_ (B_ * S_)          // 4096 token rows
#define SH_ (S_ / 2)           // split-K half length (1024 keys)

#define LOG2E_   1.44269504088896f
#define CSCALE_  (0.125f * LOG2E_)   // score scale folded into log2-domain

typedef float f32x4 __attribute__((ext_vector_type(4)));
typedef int   i32x4 __attribute__((ext_vector_type(4)));

__device__ __forceinline__ float bf2f(unsigned short u) {
    union { unsigned int i; float f; } c; c.i = ((unsigned int)u) << 16; return c.f;
}
__device__ __forceinline__ unsigned short f2bf(float f) {
    union { float f; unsigned int i; } c; c.f = f;
    unsigned int r = c.i + 0x7FFFu + ((c.i >> 16) & 1u);
    return (unsigned short)(r >> 16);
}
__device__ __forceinline__ unsigned int cvtpk_bf16(float lo, float hi) {
    unsigned int r;
    asm volatile("v_cvt_pk_bf16_f32 %0, %1, %2" : "=v"(r) : "v"(lo), "v"(hi));
    return r;
}
__device__ __forceinline__ void gl_lds16(const void* g, void* l) {
    __builtin_amdgcn_global_load_lds((const __attribute__((address_space(1))) void*)g,
                                     (__attribute__((address_space(3))) void*)l, 16, 0, 0);
}
__device__ __forceinline__ void mfma_bf16(f32x4& d, i32x4 a, i32x4 b) {
    asm volatile("v_mfma_f32_16x16x32_bf16 %0, %1, %2, %0" : "+v"(d) : "v"(a), "v"(b));
}

// ---------------------------------------------------------------------------
// elementwise fp32 -> bf16 (8 elems/thread)
// ---------------------------------------------------------------------------
__global__ __launch_bounds__(256) void convert_f32_bf16(
    const float* __restrict__ in, unsigned short* __restrict__ out, int n)
{
    const int i = (blockIdx.x * 256 + threadIdx.x) * 8;
    if (i >= n) return;
    const float4 a = *reinterpret_cast<const float4*>(in + i);
    const float4 b = *reinterpret_cast<const float4*>(in + i + 4);
    ushort4 u0 = make_ushort4(f2bf(a.x), f2bf(a.y), f2bf(a.z), f2bf(a.w));
    ushort4 u1 = make_ushort4(f2bf(b.x), f2bf(b.y), f2bf(b.z), f2bf(b.w));
    *reinterpret_cast<ushort4*>(out + i)     = u0;
    *reinterpret_cast<ushort4*>(out + i + 4) = u1;
}

// ---------------------------------------------------------------------------
// mask -> mask * log2e  (exp2-domain softmax)
// ---------------------------------------------------------------------------
__global__ __launch_bounds__(256) void scale_mask(
    const float* __restrict__ m, float* __restrict__ m2, int n)
{
    const int i = blockIdx.x * 256 + threadIdx.x;
    if (i < n) m2[i] = m[i] * LOG2E_;
}

// ---------------------------------------------------------------------------
// transpose + convert: W[K][N] fp32 -> Wt[N][K] bf16
// ---------------------------------------------------------------------------
__global__ __launch_bounds__(256) void transpose_cvt(
    const float* __restrict__ W, unsigned short* __restrict__ Wt, int K, int N)
{
    __shared__ float t[32][33];
    const int n0 = blockIdx.x * 32, k0 = blockIdx.y * 32;
    const int tx = threadIdx.x & 31, ty = threadIdx.x >> 5;   // ty 0..7
#pragma unroll
    for (int r = 0; r < 32; r += 8)
        t[ty + r][tx] = W[(size_t)(k0 + ty + r) * N + n0 + tx];
    __syncthreads();
#pragma unroll
    for (int r = 0; r < 32; r += 8)
        Wt[(size_t)(n0 + ty + r) * K + k0 + tx] = f2bf(t[tx][ty + r]);
}

// ---------------------------------------------------------------------------
// GEMM: C[M,N] = A[M,K]_bf16 * Bt[N,K]_bf16^T + bias   (r8-verified)
// ---------------------------------------------------------------------------
template <typename OutT, int BN>
__global__ __launch_bounds__(256) void gemm_bt_bf16(
    const unsigned short* __restrict__ A,   // [M][K]
    const unsigned short* __restrict__ Bt,  // [N][K]
    const float* __restrict__ bias,         // [N]
    OutT* __restrict__ C, int M, int N, int K)
{
    constexpr int NW = BN / 2;    // wave n-extent
    constexpr int NI = NW / 16;   // n-frags per wave
    __shared__ alignas(16) unsigned short As[2][4096];
    __shared__ alignas(16) unsigned short Bs[2][BN * 32];

    const int tid  = threadIdx.x;
    const int wave = tid >> 6;
    const int l    = tid & 63;
    const int g    = l >> 4;
    const int r    = l & 15;
    const int wr   = wave >> 1, wc = wave & 1;
    const int row0 = blockIdx.y * 128;
    const int col0 = blockIdx.x * BN;

    const size_t aoff0 = (size_t)(row0 +   0 + l) * K + wave * 8;
    const size_t aoff1 = (size_t)(row0 +  64 + l) * K + wave * 8;
    const size_t boff0 = (size_t)(col0 +   0 + l) * K + wave * 8;
    const size_t boff1 = (size_t)(col0 +  64 + l) * K + wave * 8;  // BN=128 only

    auto stage = [&](int kt, int buf) {
        gl_lds16(A + aoff0 + kt, &As[buf][wave * 1024]);
        gl_lds16(A + aoff1 + kt, &As[buf][wave * 1024 + 512]);
        if constexpr (BN == 128) {
            gl_lds16(Bt + boff0 + kt, &Bs[buf][wave * 1024]);
            gl_lds16(Bt + boff1 + kt, &Bs[buf][wave * 1024 + 512]);
        } else {
            gl_lds16(Bt + boff0 + kt, &Bs[buf][wave * 512]);
        }
    };

    f32x4 acc[4][NI];
#pragma unroll
    for (int mi = 0; mi < 4; ++mi)
#pragma unroll
        for (int ni = 0; ni < NI; ++ni) acc[mi][ni] = (f32x4)0.f;

    stage(0, 0);
    __syncthreads();

    for (int kt = 0; kt < K; kt += 32) {
        const int cur = (kt >> 5) & 1;
        if (kt + 32 < K) stage(kt + 32, cur ^ 1);

        const unsigned short* Ab = &As[cur][g * 1024];
        const unsigned short* Bb = &Bs[cur][g * (BN * 8)];
        i32x4 af[4], bf[NI];
#pragma unroll
        for (int mi = 0; mi < 4; ++mi)
            af[mi] = *reinterpret_cast<const i32x4*>(Ab + (wr * 64 + mi * 16 + r) * 8);
#pragma unroll
        for (int ni = 0; ni < NI; ++ni)
            bf[ni] = *reinterpret_cast<const i32x4*>(Bb + (wc * NW + ni * 16 + r) * 8);
#pragma unroll
        for (int mi = 0; mi < 4; ++mi)
#pragma unroll
            for (int ni = 0; ni < NI; ++ni)
                mfma_bf16(acc[mi][ni], af[mi], bf[ni]);

        __syncthreads();   // drains gl_lds (vmcnt) + ds reads; next buf ready
    }

#pragma unroll
    for (int ni = 0; ni < NI; ++ni) {
        const int n = col0 + wc * NW + ni * 16 + r;
        const float bv = bias[n];
#pragma unroll
        for (int mi = 0; mi < 4; ++mi) {
#pragma unroll
            for (int e = 0; e < 4; ++e) {
                const int m = row0 + wr * 64 + mi * 16 + g * 4 + e;
                const float val = acc[mi][ni][e] + bv;
                if constexpr (sizeof(OutT) == 2)
                    C[(size_t)m * N + n] = (OutT)f2bf(val);
                else
                    C[(size_t)m * N + n] = (OutT)val;
            }
        }
    }
}

// ---------------------------------------------------------------------------
// Split-K MFMA flash attention, pass 1.
// grid (S/128, H, B*2): blockIdx.z = b*2 + half; keys [half*1024, +1024).
// Body = r8-verified structure (8 waves x 16 q-rows, KV tile 64, dbuf,
// 1 barrier/tile) + exp2-domain softmax + defer-max. No setprio.
// Epilogue: normalized partial O (bf16) to op0/op1; per-row (m,l) f32.
// 1024 blocks -> 4 blocks/CU -> 32 waves/CU.
// ---------------------------------------------------------------------------
__global__ __launch_bounds__(512) void flash_attn_split(
    const unsigned short* __restrict__ qkv,  // [BS][3072]
    const float* __restrict__ mask2,         // [B][S]  (mask * log2e)
    unsigned short* __restrict__ op0,        // [BS][1024] partial half 0
    unsigned short* __restrict__ op1,        // [BS][1024] partial half 1
    float2* __restrict__ ml)                 // [2][B][H][S] (m, l)
{
    __shared__ alignas(16) unsigned short Klds[2][4096];  // [key][d^((key&7)<<3)]
    __shared__ alignas(16) unsigned short Vt[2][4096];    // [d][key^((d&7)<<3)]

    const int tid  = threadIdx.x;
    const int wave = tid >> 6;          // 0..7
    const int l    = tid & 63;
    const int g    = l >> 4;
    const int r    = l & 15;
    const int z    = blockIdx.z;
    const int b    = z >> 1;
    const int half = z & 1;
    const int kv0  = half * SH_;
    const int h    = blockIdx.y;
    const int q0   = blockIdx.x * 128;
    const int qw   = q0 + wave * 16;    // this wave's 16 q-rows

    const size_t rs = 3 * (size_t)D_;
    const unsigned short* qb = qkv + (size_t)b * S_ * rs + (size_t)h * HD_;
    const unsigned short* kb = qb + D_;
    const unsigned short* vb = qb + 2 * D_;
    const float* m2row = mask2 + (size_t)b * S_;

    // Q fragments: q = qw + r, d = ks*32 + g*8 + j
    i32x4 qf[2];
#pragma unroll
    for (int ks = 0; ks < 2; ++ks)
        qf[ks] = *reinterpret_cast<const i32x4*>(
            qb + (size_t)(qw + r) * rs + ks * 32 + g * 8);

    // K staging (waves 0-3, r4 mapping): keys kt + wave*16 + t*8 + (l>>3)
    const int kkey = (wave & 3) * 16 + (l >> 3);
    const int kuni = ((l & 7) ^ (l >> 3)) * 8;
    // V staging (waves 4-7, r4 mapping with w' = wave-4)
    const int vkey = (wave & 3) * 16 + (l >> 2);
    const int vpart = l & 3;

    auto stage = [&](int kt, int buf) {
        if (wave < 4) {
            gl_lds16(kb + (size_t)(kt + kkey) * rs + kuni,
                     &Klds[buf][(wave & 3) * 1024]);
            gl_lds16(kb + (size_t)(kt + kkey + 8) * rs + kuni,
                     &Klds[buf][(wave & 3) * 1024 + 512]);
        } else {
#pragma unroll
            for (int p = 0; p < 4; ++p) {
                const int d0 = p * 16 + vpart * 4;
                const ushort4 vv = *reinterpret_cast<const ushort4*>(
                    vb + (size_t)(kt + vkey) * rs + d0);
                Vt[buf][(d0 + 0) * 64 + (vkey ^ (((d0 + 0) & 7) << 3))] = vv.x;
                Vt[buf][(d0 + 1) * 64 + (vkey ^ (((d0 + 1) & 7) << 3))] = vv.y;
                Vt[buf][(d0 + 2) * 64 + (vkey ^ (((d0 + 2) & 7) << 3))] = vv.z;
                Vt[buf][(d0 + 3) * 64 + (vkey ^ (((d0 + 3) & 7) << 3))] = vv.w;
            }
        }
    };

    f32x4 acc[4];     // O^T: d = mi*16 + g*4 + e, q = r
    float m_i = -1e30f, l_i = 0.f;
#pragma unroll
    for (int mi = 0; mi < 4; ++mi) acc[mi] = (f32x4)0.f;

    stage(kv0, 0);
    __syncthreads();

    for (int kt = kv0; kt < kv0 + SH_; kt += 64) {
        const int cur = ((kt - kv0) >> 6) & 1;
        if (kt + 64 < kv0 + SH_) stage(kt + 64, cur ^ 1);

        const unsigned short* Kb = Klds[cur];
        const unsigned short* Vb = Vt[cur];

        // --- S^T = K · Q^T : s[mi], key = kt + mi*16 + g*4 + e, q = r ---
        f32x4 s[4];
#pragma unroll
        for (int mi = 0; mi < 4; ++mi) s[mi] = (f32x4)0.f;
#pragma unroll
        for (int ks = 0; ks < 2; ++ks)
#pragma unroll
            for (int mi = 0; mi < 4; ++mi) {
                const i32x4 kf = *reinterpret_cast<const i32x4*>(
                    Kb + (mi * 16 + r) * 64 + ((ks * 32 + g * 8) ^ ((r & 7) << 3)));
                mfma_bf16(s[mi], kf, qf[ks]);
            }

        // --- scale + mask in log2 domain ---
#pragma unroll
        for (int mi = 0; mi < 4; ++mi) {
            const float4 mk = *reinterpret_cast<const float4*>(
                m2row + kt + mi * 16 + g * 4);
            s[mi][0] = s[mi][0] * CSCALE_ + mk.x;
            s[mi][1] = s[mi][1] * CSCALE_ + mk.y;
            s[mi][2] = s[mi][2] * CSCALE_ + mk.z;
            s[mi][3] = s[mi][3] * CSCALE_ + mk.w;
        }

        // --- online softmax (log2 domain), per-q-row stats, defer-max ---
        float tmax = -1e30f;
#pragma unroll
        for (int mi = 0; mi < 4; ++mi)
#pragma unroll
            for (int e = 0; e < 4; ++e)
                tmax = fmaxf(tmax, s[mi][e]);
        tmax = fmaxf(tmax, __shfl_xor(tmax, 16));
        tmax = fmaxf(tmax, __shfl_xor(tmax, 32));
        if (tmax > m_i + 4.f) {
            const float corr = exp2f(m_i - tmax);
            l_i *= corr;
#pragma unroll
            for (int mi = 0; mi < 4; ++mi) acc[mi] *= corr;
            m_i = tmax;
        }

        unsigned int pk[4][2];   // [mi][wl]: keys (mi*16 + g*4 + 2wl, +1)
        float ls = 0.f;
#pragma unroll
        for (int mi = 0; mi < 4; ++mi) {
            const float p0 = exp2f(s[mi][0] - m_i);
            const float p1 = exp2f(s[mi][1] - m_i);
            const float p2 = exp2f(s[mi][2] - m_i);
            const float p3 = exp2f(s[mi][3] - m_i);
            ls += (p0 + p1) + (p2 + p3);
            pk[mi][0] = cvtpk_bf16(p0, p1);
            pk[mi][1] = cvtpk_bf16(p2, p3);
        }
        l_i += ls;               // lane-partial over g; reduced at end

        // --- PV: O^T += V^T · P^T ---
#pragma unroll
        for (int ks = 0; ks < 2; ++ks) {
            i32x4 pf;   // word w = keys ks*32 + g*8 + 2w, +1 of q-row r
#pragma unroll
            for (int w = 0; w < 4; ++w) {
                const int src = (((g & 1) * 2 + (w >> 1)) << 4) + r;
                const unsigned int vA = __shfl(pk[2 * ks + 0][w & 1], src);
                const unsigned int vB = __shfl(pk[2 * ks + 1][w & 1], src);
                pf[w] = (int)((g >> 1) ? vB : vA);
            }
#pragma unroll
            for (int mi = 0; mi < 4; ++mi) {
                const i32x4 vf = *reinterpret_cast<const i32x4*>(
                    Vb + (mi * 16 + r) * 64 + ((ks * 32 + g * 8) ^ ((r & 7) << 3)));
                mfma_bf16(acc[mi], vf, pf);
            }
        }

        __syncthreads();   // drains stage's vmcnt/lgkm; next buf ready
    }

    // --- epilogue: reduce l over g-lanes, write normalized partial + (m,l) ---
    float lf = l_i;
    lf += __shfl_xor(lf, 16);
    lf += __shfl_xor(lf, 32);
    const float inv = 1.0f / lf;
    const size_t token = (size_t)b * S_ + qw + r;
    unsigned short* obase = half ? op1 : op0;
#pragma unroll
    for (int mi = 0; mi < 4; ++mi) {
        const f32x4 v = acc[mi] * inv;
        uint2 w;
        w.x = cvtpk_bf16(v[0], v[1]);
        w.y = cvtpk_bf16(v[2], v[3]);
        *reinterpret_cast<uint2*>(
            obase + token * D_ + h * HD_ + mi * 16 + g * 4) = w;
    }
    if (l < 16) {   // g==0 lane per q-row
        const size_t mli = (((size_t)half * B_ + b) * H_ + h) * S_ + qw + l;
        ml[mli] = make_float2(m_i, lf);
    }
}

// ---------------------------------------------------------------------------
// Split-K combine: out = (w0*O0 + w1*O1) / (w0+w1), w_h = l_h * 2^(m_h - M).
// In-place on o0 (same-element RMW). 8 dims per thread.
// ---------------------------------------------------------------------------
__global__ __launch_bounds__(256) void combine_halves(
    unsigned short* o0,                       // [BS][1024] in/out (half 0)
    const unsigned short* __restrict__ o1,    // [BS][1024] (half 1)
    const float2* __restrict__ ml)            // [2][B][H][S]
{
    const int gid   = blockIdx.x * 256 + threadIdx.x;   // 0 .. 524287
    const int chunk = gid & 127;                         // 8-elem chunk in row
    const int token = gid >> 7;                          // 0..4095
    const int h     = chunk >> 3;
    const int b     = token >> 11;
    const int q     = token & 2047;

    const size_t mli = (((size_t)b) * H_ + h) * S_ + q;
    const float2 a0 = ml[mli];
    const float2 a1 = ml[(size_t)B_ * H_ * S_ + mli];
    const float M  = fmaxf(a0.x, a1.x);
    float w0 = a0.y * exp2f(a0.x - M);
    float w1 = a1.y * exp2f(a1.x - M);
    const float inv = 1.0f / (w0 + w1);
    w0 *= inv; w1 *= inv;

    const size_t off = (size_t)token * D_ + chunk * 8;
    const ushort4 x0 = *reinterpret_cast<const ushort4*>(o0 + off);
    const ushort4 x1 = *reinterpret_cast<const ushort4*>(o0 + off + 4);
    const ushort4 y0 = *reinterpret_cast<const ushort4*>(o1 + off);
    const ushort4 y1 = *reinterpret_cast<const ushort4*>(o1 + off + 4);
    ushort4 r0, r1;
    r0.x = f2bf(w0 * bf2f(x0.x) + w1 * bf2f(y0.x));
    r0.y = f2bf(w0 * bf2f(x0.y) + w1 * bf2f(y0.y));
    r0.z = f2bf(w0 * bf2f(x0.z) + w1 * bf2f(y0.z));
    r0.w = f2bf(w0 * bf2f(x0.w) + w1 * bf2f(y0.w));
    r1.x = f2bf(w0 * bf2f(x1.x) + w1 * bf2f(y1.x));
    r1.y = f2bf(w0 * bf2f(x1.y) + w1 * bf2f(y1.y));
    r1.z = f2bf(w0 * bf2f(x1.z) + w1 * bf2f(y1.z));
    r1.w = f2bf(w0 * bf2f(x1.w) + w1 * bf2f(y1.w));
    *reinterpret_cast<ushort4*>(o0 + off)     = r0;
    *reinterpret_cast<ushort4*>(o0 + off + 4) = r1;
}

// ---------------------------------------------------------------------------
extern "C" void kernel_launch(void* const* d_in, const int* in_sizes, int n_in,
                              void* d_out, int out_size, void* d_ws, size_t ws_size,
                              hipStream_t stream)
{
    const float* x      = (const float*)d_in[0];   // [2,2048,1024]
    const float* amask  = (const float*)d_in[1];   // [2,2048]
    const float* w_attn = (const float*)d_in[2];   // [1024,3072]
    const float* b_attn = (const float*)d_in[3];   // [3072]
    const float* w_proj = (const float*)d_in[4];   // [1024,1024]
    const float* b_proj = (const float*)d_in[5];   // [1024]
    float* out = (float*)d_out;                    // [2,2048,1024] fp32

    unsigned short* qkvb  = (unsigned short*)d_ws;                  // [4096][3072] bf16
    unsigned short* attnb = qkvb  + (size_t)BS_ * 3 * D_;           // [4096][1024] bf16 (partial 0 / final)
    unsigned short* xb    = attnb + (size_t)BS_ * D_;               // [4096][1024] bf16 (x, then partial 1)
    unsigned short* wat   = xb    + (size_t)BS_ * D_;               // [3072][1024] bf16 (w_attn^T, then ml)
    unsigned short* wpt   = wat   + (size_t)3 * D_ * D_;            // [1024][1024] bf16
    float*          mask2 = (float*)(wpt + (size_t)D_ * D_);        // [4096] f32
    float2*         mlbuf = (float2*)wat;                           // [2][B][H][S] (1 MB, overlays wat)

    convert_f32_bf16<<<(BS_ * D_) / 2048, 256, 0, stream>>>(x, xb, BS_ * D_);
    scale_mask<<<BS_ / 256, 256, 0, stream>>>(amask, mask2, BS_);
    transpose_cvt<<<dim3(3 * D_ / 32, D_ / 32), 256, 0, stream>>>(w_attn, wat, D_, 3 * D_);
    transpose_cvt<<<dim3(D_ / 32, D_ / 32), 256, 0, stream>>>(w_proj, wpt, D_, D_);

    // 1) QKV projection (bf16 MFMA) -> bf16 qkv   (reads xb, wat)
    gemm_bt_bf16<unsigned short, 128><<<dim3(3 * D_ / 128, BS_ / 128), 256, 0, stream>>>(
        xb, wat, b_attn, qkvb, BS_, 3 * D_, D_);

    // 2) split-K flash pass 1: partials into attnb (half 0) / xb (half 1),
    //    (m,l) into mlbuf (overlays dead wat region)
    flash_attn_split<<<dim3(S_ / 128, H_, B_ * 2), 512, 0, stream>>>(
        qkvb, mask2, attnb, xb, mlbuf);

    // 3) combine halves in-place into attnb
    combine_halves<<<(BS_ * D_ / 8) / 256, 256, 0, stream>>>(attnb, xb, mlbuf);

    // 4) output projection (bf16 MFMA) -> fp32 out
    gemm_bt_bf16<float, 128><<<dim3(D_ / 128, BS_ / 128), 256, 0, stream>>>(
        attnb, wpt, b_proj, out, BS_, D_, D_);
}

// Round 12
// 185.782 us; speedup vs baseline: 1.0586x; 1.0586x over previous
//
#include <hip/hip_runtime.h>
#include <math.h>

#define B_  2
#define S_  2048
#define D_  1024
#define H_  16
#define HD_ 64
#define BS_ (B_ * S_)          // 4096 token rows

#define LOG2E_   1.44269504088896f
#define CSCALE_  (0.125f * LOG2E_)   // score scale folded into log2-domain

typedef float f32x4 __attribute__((ext_vector_type(4)));
typedef int   i32x4 __attribute__((ext_vector_type(4)));

__device__ __forceinline__ float bf2f(unsigned short u) {
    union { unsigned int i; float f; } c; c.i = ((unsigned int)u) << 16; return c.f;
}
__device__ __forceinline__ unsigned short f2bf(float f) {
    union { float f; unsigned int i; } c; c.f = f;
    unsigned int r = c.i + 0x7FFFu + ((c.i >> 16) & 1u);
    return (unsigned short)(r >> 16);
}
__device__ __forceinline__ unsigned int cvtpk_bf16(float lo, float hi) {
    unsigned int r;
    asm volatile("v_cvt_pk_bf16_f32 %0, %1, %2" : "=v"(r) : "v"(lo), "v"(hi));
    return r;
}
__device__ __forceinline__ void gl_lds16(const void* g, void* l) {
    __builtin_amdgcn_global_load_lds((const __attribute__((address_space(1))) void*)g,
                                     (__attribute__((address_space(3))) void*)l, 16, 0, 0);
}
__device__ __forceinline__ void mfma_bf16(f32x4& d, i32x4 a, i32x4 b) {
    asm volatile("v_mfma_f32_16x16x32_bf16 %0, %1, %2, %0" : "+v"(d) : "v"(a), "v"(b));
}

// ---------------------------------------------------------------------------
// elementwise fp32 -> bf16 (8 elems/thread)
// ---------------------------------------------------------------------------
__global__ __launch_bounds__(256) void convert_f32_bf16(
    const float* __restrict__ in, unsigned short* __restrict__ out, int n)
{
    const int i = (blockIdx.x * 256 + threadIdx.x) * 8;
    if (i >= n) return;
    const float4 a = *reinterpret_cast<const float4*>(in + i);
    const float4 b = *reinterpret_cast<const float4*>(in + i + 4);
    ushort4 u0 = make_ushort4(f2bf(a.x), f2bf(a.y), f2bf(a.z), f2bf(a.w));
    ushort4 u1 = make_ushort4(f2bf(b.x), f2bf(b.y), f2bf(b.z), f2bf(b.w));
    *reinterpret_cast<ushort4*>(out + i)     = u0;
    *reinterpret_cast<ushort4*>(out + i + 4) = u1;
}

// ---------------------------------------------------------------------------
// mask -> mask * log2e  (exp2-domain softmax)
// ---------------------------------------------------------------------------
__global__ __launch_bounds__(256) void scale_mask(
    const float* __restrict__ m, float* __restrict__ m2, int n)
{
    const int i = blockIdx.x * 256 + threadIdx.x;
    if (i < n) m2[i] = m[i] * LOG2E_;
}

// ---------------------------------------------------------------------------
// transpose + convert: W[K][N] fp32 -> Wt[N][K] bf16
// ---------------------------------------------------------------------------
__global__ __launch_bounds__(256) void transpose_cvt(
    const float* __restrict__ W, unsigned short* __restrict__ Wt, int K, int N)
{
    __shared__ float t[32][33];
    const int n0 = blockIdx.x * 32, k0 = blockIdx.y * 32;
    const int tx = threadIdx.x & 31, ty = threadIdx.x >> 5;   // ty 0..7
#pragma unroll
    for (int r = 0; r < 32; r += 8)
        t[ty + r][tx] = W[(size_t)(k0 + ty + r) * N + n0 + tx];
    __syncthreads();
#pragma unroll
    for (int r = 0; r < 32; r += 8)
        Wt[(size_t)(n0 + ty + r) * K + k0 + tx] = f2bf(t[tx][ty + r]);
}

// ---------------------------------------------------------------------------
// GEMM: C[M,N] = A[M,K]_bf16 * Bt[N,K]_bf16^T + bias   (r8-verified)
// BN=128: 4-wave 2x2, wave 64x64. BN=64: 4-wave 2x2, wave 64x32 (2x grid).
// ---------------------------------------------------------------------------
template <typename OutT, int BN>
__global__ __launch_bounds__(256) void gemm_bt_bf16(
    const unsigned short* __restrict__ A,   // [M][K]
    const unsigned short* __restrict__ Bt,  // [N][K]
    const float* __restrict__ bias,         // [N]
    OutT* __restrict__ C, int M, int N, int K)
{
    constexpr int NW = BN / 2;    // wave n-extent
    constexpr int NI = NW / 16;   // n-frags per wave
    __shared__ alignas(16) unsigned short As[2][4096];
    __shared__ alignas(16) unsigned short Bs[2][BN * 32];

    const int tid  = threadIdx.x;
    const int wave = tid >> 6;
    const int l    = tid & 63;
    const int g    = l >> 4;
    const int r    = l & 15;
    const int wr   = wave >> 1, wc = wave & 1;
    const int row0 = blockIdx.y * 128;
    const int col0 = blockIdx.x * BN;

    const size_t aoff0 = (size_t)(row0 +   0 + l) * K + wave * 8;
    const size_t aoff1 = (size_t)(row0 +  64 + l) * K + wave * 8;
    const size_t boff0 = (size_t)(col0 +   0 + l) * K + wave * 8;
    const size_t boff1 = (size_t)(col0 +  64 + l) * K + wave * 8;  // BN=128 only

    auto stage = [&](int kt, int buf) {
        gl_lds16(A + aoff0 + kt, &As[buf][wave * 1024]);
        gl_lds16(A + aoff1 + kt, &As[buf][wave * 1024 + 512]);
        if constexpr (BN == 128) {
            gl_lds16(Bt + boff0 + kt, &Bs[buf][wave * 1024]);
            gl_lds16(Bt + boff1 + kt, &Bs[buf][wave * 1024 + 512]);
        } else {
            gl_lds16(Bt + boff0 + kt, &Bs[buf][wave * 512]);
        }
    };

    f32x4 acc[4][NI];
#pragma unroll
    for (int mi = 0; mi < 4; ++mi)
#pragma unroll
        for (int ni = 0; ni < NI; ++ni) acc[mi][ni] = (f32x4)0.f;

    stage(0, 0);
    __syncthreads();

    for (int kt = 0; kt < K; kt += 32) {
        const int cur = (kt >> 5) & 1;
        if (kt + 32 < K) stage(kt + 32, cur ^ 1);

        const unsigned short* Ab = &As[cur][g * 1024];
        const unsigned short* Bb = &Bs[cur][g * (BN * 8)];
        i32x4 af[4], bf[NI];
#pragma unroll
        for (int mi = 0; mi < 4; ++mi)
            af[mi] = *reinterpret_cast<const i32x4*>(Ab + (wr * 64 + mi * 16 + r) * 8);
#pragma unroll
        for (int ni = 0; ni < NI; ++ni)
            bf[ni] = *reinterpret_cast<const i32x4*>(Bb + (wc * NW + ni * 16 + r) * 8);
#pragma unroll
        for (int mi = 0; mi < 4; ++mi)
#pragma unroll
            for (int ni = 0; ni < NI; ++ni)
                mfma_bf16(acc[mi][ni], af[mi], bf[ni]);

        __syncthreads();   // drains gl_lds (vmcnt) + ds reads; next buf ready
    }

#pragma unroll
    for (int ni = 0; ni < NI; ++ni) {
        const int n = col0 + wc * NW + ni * 16 + r;
        const float bv = bias[n];
#pragma unroll
        for (int mi = 0; mi < 4; ++mi) {
#pragma unroll
            for (int e = 0; e < 4; ++e) {
                const int m = row0 + wr * 64 + mi * 16 + g * 4 + e;
                const float val = acc[mi][ni][e] + bv;
                if constexpr (sizeof(OutT) == 2)
                    C[(size_t)m * N + n] = (OutT)f2bf(val);
                else
                    C[(size_t)m * N + n] = (OutT)val;
            }
        }
    }
}

// ---------------------------------------------------------------------------
// MFMA flash attention, 8 waves x 16 q-rows, Q tile 128, KV tile 64.
// r8-verified structure (32 KB LDS, dbuf, 1 barrier/tile, role-split staging)
// + exp2-domain softmax + defer-max (THR=4). No setprio (m190/r10: hurts
// barrier-lockstep blocks). Single-pass over keys.
// ---------------------------------------------------------------------------
__global__ __launch_bounds__(512) void flash_attn_mfma(
    const unsigned short* __restrict__ qkv,  // [BS][3072]
    const float* __restrict__ mask2,         // [B][S]  (mask * log2e)
    unsigned short* __restrict__ out)        // [BS][1024]
{
    __shared__ alignas(16) unsigned short Klds[2][4096];  // [key][d^((key&7)<<3)]
    __shared__ alignas(16) unsigned short Vt[2][4096];    // [d][key^((d&7)<<3)]

    const int tid  = threadIdx.x;
    const int wave = tid >> 6;          // 0..7
    const int l    = tid & 63;
    const int g    = l >> 4;
    const int r    = l & 15;
    const int b    = blockIdx.z;
    const int h    = blockIdx.y;
    const int q0   = blockIdx.x * 128;
    const int qw   = q0 + wave * 16;    // this wave's 16 q-rows

    const size_t rs = 3 * (size_t)D_;
    const unsigned short* qb = qkv + (size_t)b * S_ * rs + (size_t)h * HD_;
    const unsigned short* kb = qb + D_;
    const unsigned short* vb = qb + 2 * D_;
    const float* m2row = mask2 + (size_t)b * S_;

    // Q fragments: q = qw + r, d = ks*32 + g*8 + j
    i32x4 qf[2];
#pragma unroll
    for (int ks = 0; ks < 2; ++ks)
        qf[ks] = *reinterpret_cast<const i32x4*>(
            qb + (size_t)(qw + r) * rs + ks * 32 + g * 8);

    // K staging (waves 0-3, r4 mapping): keys wave*16 + t*8 + (l>>3)
    const int kkey = (wave & 3) * 16 + (l >> 3);
    const int kuni = ((l & 7) ^ (l >> 3)) * 8;
    // V staging (waves 4-7, r4 mapping with w' = wave-4)
    const int vkey = (wave & 3) * 16 + (l >> 2);
    const int vpart = l & 3;

    auto stage = [&](int kt, int buf) {
        if (wave < 4) {
            gl_lds16(kb + (size_t)(kt + kkey) * rs + kuni,
                     &Klds[buf][(wave & 3) * 1024]);
            gl_lds16(kb + (size_t)(kt + kkey + 8) * rs + kuni,
                     &Klds[buf][(wave & 3) * 1024 + 512]);
        } else {
#pragma unroll
            for (int p = 0; p < 4; ++p) {
                const int d0 = p * 16 + vpart * 4;
                const ushort4 vv = *reinterpret_cast<const ushort4*>(
                    vb + (size_t)(kt + vkey) * rs + d0);
                Vt[buf][(d0 + 0) * 64 + (vkey ^ (((d0 + 0) & 7) << 3))] = vv.x;
                Vt[buf][(d0 + 1) * 64 + (vkey ^ (((d0 + 1) & 7) << 3))] = vv.y;
                Vt[buf][(d0 + 2) * 64 + (vkey ^ (((d0 + 2) & 7) << 3))] = vv.z;
                Vt[buf][(d0 + 3) * 64 + (vkey ^ (((d0 + 3) & 7) << 3))] = vv.w;
            }
        }
    };

    f32x4 acc[4];     // O^T: d = mi*16 + g*4 + e, q = r
    float m_i = -1e30f, l_i = 0.f;
#pragma unroll
    for (int mi = 0; mi < 4; ++mi) acc[mi] = (f32x4)0.f;

    stage(0, 0);
    __syncthreads();

    for (int kt = 0; kt < S_; kt += 64) {
        const int cur = (kt >> 6) & 1;
        if (kt + 64 < S_) stage(kt + 64, cur ^ 1);

        const unsigned short* Kb = Klds[cur];
        const unsigned short* Vb = Vt[cur];

        // --- S^T = K · Q^T : s[mi], key = mi*16 + g*4 + e, q = r ---
        f32x4 s[4];
#pragma unroll
        for (int mi = 0; mi < 4; ++mi) s[mi] = (f32x4)0.f;
#pragma unroll
        for (int ks = 0; ks < 2; ++ks)
#pragma unroll
            for (int mi = 0; mi < 4; ++mi) {
                const i32x4 kf = *reinterpret_cast<const i32x4*>(
                    Kb + (mi * 16 + r) * 64 + ((ks * 32 + g * 8) ^ ((r & 7) << 3)));
                mfma_bf16(s[mi], kf, qf[ks]);
            }

        // --- scale + mask in log2 domain ---
#pragma unroll
        for (int mi = 0; mi < 4; ++mi) {
            const float4 mk = *reinterpret_cast<const float4*>(
                m2row + kt + mi * 16 + g * 4);
            s[mi][0] = s[mi][0] * CSCALE_ + mk.x;
            s[mi][1] = s[mi][1] * CSCALE_ + mk.y;
            s[mi][2] = s[mi][2] * CSCALE_ + mk.z;
            s[mi][3] = s[mi][3] * CSCALE_ + mk.w;
        }

        // --- online softmax (log2 domain) + defer-max (THR=4) ---
        float tmax = -1e30f;
#pragma unroll
        for (int mi = 0; mi < 4; ++mi)
#pragma unroll
            for (int e = 0; e < 4; ++e)
                tmax = fmaxf(tmax, s[mi][e]);
        tmax = fmaxf(tmax, __shfl_xor(tmax, 16));
        tmax = fmaxf(tmax, __shfl_xor(tmax, 32));
        if (tmax > m_i + 4.f) {            // wave-uniform branch
            const float corr = exp2f(m_i - tmax);
            l_i *= corr;
#pragma unroll
            for (int mi = 0; mi < 4; ++mi) acc[mi] *= corr;
            m_i = tmax;
        }

        unsigned int pk[4][2];   // [mi][wl]: keys (mi*16 + g*4 + 2wl, +1)
        float ls = 0.f;
#pragma unroll
        for (int mi = 0; mi < 4; ++mi) {
            const float p0 = exp2f(s[mi][0] - m_i);
            const float p1 = exp2f(s[mi][1] - m_i);
            const float p2 = exp2f(s[mi][2] - m_i);
            const float p3 = exp2f(s[mi][3] - m_i);
            ls += (p0 + p1) + (p2 + p3);
            pk[mi][0] = cvtpk_bf16(p0, p1);
            pk[mi][1] = cvtpk_bf16(p2, p3);
        }
        l_i += ls;               // lane-partial over g; reduced at end

        // --- PV: O^T += V^T · P^T ---
#pragma unroll
        for (int ks = 0; ks < 2; ++ks) {
            i32x4 pf;   // word w = keys ks*32 + g*8 + 2w, +1 of q-row r
#pragma unroll
            for (int w = 0; w < 4; ++w) {
                const int src = (((g & 1) * 2 + (w >> 1)) << 4) + r;
                const unsigned int vA = __shfl(pk[2 * ks + 0][w & 1], src);
                const unsigned int vB = __shfl(pk[2 * ks + 1][w & 1], src);
                pf[w] = (int)((g >> 1) ? vB : vA);
            }
#pragma unroll
            for (int mi = 0; mi < 4; ++mi) {
                const i32x4 vf = *reinterpret_cast<const i32x4*>(
                    Vb + (mi * 16 + r) * 64 + ((ks * 32 + g * 8) ^ ((r & 7) << 3)));
                mfma_bf16(acc[mi], vf, pf);
            }
        }

        __syncthreads();   // drains stage's vmcnt/lgkm; next buf ready
    }

    // --- epilogue: reduce l over g-lanes, divide, store bf16 ---
    float lf = l_i;
    lf += __shfl_xor(lf, 16);
    lf += __shfl_xor(lf, 32);
    const float inv = 1.0f / lf;
    const size_t token = (size_t)b * S_ + qw + r;
#pragma unroll
    for (int mi = 0; mi < 4; ++mi) {
        const f32x4 v = acc[mi] * inv;
        uint2 w;
        w.x = cvtpk_bf16(v[0], v[1]);
        w.y = cvtpk_bf16(v[2], v[3]);
        *reinterpret_cast<uint2*>(
            out + token * D_ + h * HD_ + mi * 16 + g * 4) = w;
    }
}

// ---------------------------------------------------------------------------
extern "C" void kernel_launch(void* const* d_in, const int* in_sizes, int n_in,
                              void* d_out, int out_size, void* d_ws, size_t ws_size,
                              hipStream_t stream)
{
    const float* x      = (const float*)d_in[0];   // [2,2048,1024]
    const float* amask  = (const float*)d_in[1];   // [2,2048]
    const float* w_attn = (const float*)d_in[2];   // [1024,3072]
    const float* b_attn = (const float*)d_in[3];   // [3072]
    const float* w_proj = (const float*)d_in[4];   // [1024,1024]
    const float* b_proj = (const float*)d_in[5];   // [1024]
    float* out = (float*)d_out;                    // [2,2048,1024] fp32

    unsigned short* qkvb  = (unsigned short*)d_ws;                  // [4096][3072] bf16
    unsigned short* attnb = qkvb  + (size_t)BS_ * 3 * D_;           // [4096][1024] bf16
    unsigned short* xb    = attnb + (size_t)BS_ * D_;               // [4096][1024] bf16
    unsigned short* wat   = xb    + (size_t)BS_ * D_;               // [3072][1024] bf16
    unsigned short* wpt   = wat   + (size_t)3 * D_ * D_;            // [1024][1024] bf16
    float*          mask2 = (float*)(wpt + (size_t)D_ * D_);        // [4096] f32

    convert_f32_bf16<<<(BS_ * D_) / 2048, 256, 0, stream>>>(x, xb, BS_ * D_);
    scale_mask<<<BS_ / 256, 256, 0, stream>>>(amask, mask2, BS_);
    transpose_cvt<<<dim3(3 * D_ / 32, D_ / 32), 256, 0, stream>>>(w_attn, wat, D_, 3 * D_);
    transpose_cvt<<<dim3(D_ / 32, D_ / 32), 256, 0, stream>>>(w_proj, wpt, D_, D_);

    // 1) QKV projection (bf16 MFMA) -> bf16 qkv
    gemm_bt_bf16<unsigned short, 128><<<dim3(3 * D_ / 128, BS_ / 128), 256, 0, stream>>>(
        xb, wat, b_attn, qkvb, BS_, 3 * D_, D_);

    // 2) MFMA flash attention -> bf16 (single-pass)
    flash_attn_mfma<<<dim3(S_ / 128, H_, B_), 512, 0, stream>>>(qkvb, mask2, attnb);

    // 3) output projection (bf16 MFMA, BN=64 -> 512 blocks = 2/CU) -> fp32
    gemm_bt_bf16<float, 64><<<dim3(D_ / 64, BS_ / 128), 256, 0, stream>>>(
        attnb, wpt, b_proj, out, BS_, D_, D_);
}

// Round 13
// 172.519 us; speedup vs baseline: 1.1400x; 1.0769x over previous
//
#include <hip/hip_runtime.h>
#include <math.h>

#define B_  2
#define S_  2048
#define D_  1024
#define H_  16
#define HD_ 64
#define BS_ (B_ * S_)          // 4096 token rows

typedef float f32x4 __attribute__((ext_vector_type(4)));
typedef int   i32x4 __attribute__((ext_vector_type(4)));

__device__ __forceinline__ float bf2f(unsigned short u) {
    union { unsigned int i; float f; } c; c.i = ((unsigned int)u) << 16; return c.f;
}
__device__ __forceinline__ unsigned short f2bf(float f) {
    union { float f; unsigned int i; } c; c.f = f;
    unsigned int r = c.i + 0x7FFFu + ((c.i >> 16) & 1u);
    return (unsigned short)(r >> 16);
}
__device__ __forceinline__ unsigned int cvtpk_bf16(float lo, float hi) {
    unsigned int r;
    asm volatile("v_cvt_pk_bf16_f32 %0, %1, %2" : "=v"(r) : "v"(lo), "v"(hi));
    return r;
}
__device__ __forceinline__ void gl_lds16(const void* g, void* l) {
    __builtin_amdgcn_global_load_lds((const __attribute__((address_space(1))) void*)g,
                                     (__attribute__((address_space(3))) void*)l, 16, 0, 0);
}
__device__ __forceinline__ void mfma_bf16(f32x4& d, i32x4 a, i32x4 b) {
    asm volatile("v_mfma_f32_16x16x32_bf16 %0, %1, %2, %0" : "+v"(d) : "v"(a), "v"(b));
}

// ---------------------------------------------------------------------------
// elementwise fp32 -> bf16 (8 elems/thread)
// ---------------------------------------------------------------------------
__global__ __launch_bounds__(256) void convert_f32_bf16(
    const float* __restrict__ in, unsigned short* __restrict__ out, int n)
{
    const int i = (blockIdx.x * 256 + threadIdx.x) * 8;
    if (i >= n) return;
    const float4 a = *reinterpret_cast<const float4*>(in + i);
    const float4 b = *reinterpret_cast<const float4*>(in + i + 4);
    ushort4 u0 = make_ushort4(f2bf(a.x), f2bf(a.y), f2bf(a.z), f2bf(a.w));
    ushort4 u1 = make_ushort4(f2bf(b.x), f2bf(b.y), f2bf(b.z), f2bf(b.w));
    *reinterpret_cast<ushort4*>(out + i)     = u0;
    *reinterpret_cast<ushort4*>(out + i + 4) = u1;
}

// ---------------------------------------------------------------------------
// transpose + convert: W[K][N] fp32 -> Wt[N][K] bf16
// ---------------------------------------------------------------------------
__global__ __launch_bounds__(256) void transpose_cvt(
    const float* __restrict__ W, unsigned short* __restrict__ Wt, int K, int N)
{
    __shared__ float t[32][33];
    const int n0 = blockIdx.x * 32, k0 = blockIdx.y * 32;
    const int tx = threadIdx.x & 31, ty = threadIdx.x >> 5;   // ty 0..7
#pragma unroll
    for (int r = 0; r < 32; r += 8)
        t[ty + r][tx] = W[(size_t)(k0 + ty + r) * N + n0 + tx];
    __syncthreads();
#pragma unroll
    for (int r = 0; r < 32; r += 8)
        Wt[(size_t)(n0 + ty + r) * K + k0 + tx] = f2bf(t[tx][ty + r]);
}

// ---------------------------------------------------------------------------
// GEMM: C[M,N] = A[M,K]_bf16 * Bt[N,K]_bf16^T + bias   (r8/r12-verified)
// BN=128: 4-wave 2x2, wave 64x64. BN=64: 4-wave 2x2, wave 64x32 (2x grid).
// ---------------------------------------------------------------------------
template <typename OutT, int BN>
__global__ __launch_bounds__(256) void gemm_bt_bf16(
    const unsigned short* __restrict__ A,   // [M][K]
    const unsigned short* __restrict__ Bt,  // [N][K]
    const float* __restrict__ bias,         // [N]
    OutT* __restrict__ C, int M, int N, int K)
{
    constexpr int NW = BN / 2;    // wave n-extent
    constexpr int NI = NW / 16;   // n-frags per wave
    __shared__ alignas(16) unsigned short As[2][4096];
    __shared__ alignas(16) unsigned short Bs[2][BN * 32];

    const int tid  = threadIdx.x;
    const int wave = tid >> 6;
    const int l    = tid & 63;
    const int g    = l >> 4;
    const int r    = l & 15;
    const int wr   = wave >> 1, wc = wave & 1;
    const int row0 = blockIdx.y * 128;
    const int col0 = blockIdx.x * BN;

    const size_t aoff0 = (size_t)(row0 +   0 + l) * K + wave * 8;
    const size_t aoff1 = (size_t)(row0 +  64 + l) * K + wave * 8;
    const size_t boff0 = (size_t)(col0 +   0 + l) * K + wave * 8;
    const size_t boff1 = (size_t)(col0 +  64 + l) * K + wave * 8;  // BN=128 only

    auto stage = [&](int kt, int buf) {
        gl_lds16(A + aoff0 + kt, &As[buf][wave * 1024]);
        gl_lds16(A + aoff1 + kt, &As[buf][wave * 1024 + 512]);
        if constexpr (BN == 128) {
            gl_lds16(Bt + boff0 + kt, &Bs[buf][wave * 1024]);
            gl_lds16(Bt + boff1 + kt, &Bs[buf][wave * 1024 + 512]);
        } else {
            gl_lds16(Bt + boff0 + kt, &Bs[buf][wave * 512]);
        }
    };

    f32x4 acc[4][NI];
#pragma unroll
    for (int mi = 0; mi < 4; ++mi)
#pragma unroll
        for (int ni = 0; ni < NI; ++ni) acc[mi][ni] = (f32x4)0.f;

    stage(0, 0);
    __syncthreads();

    for (int kt = 0; kt < K; kt += 32) {
        const int cur = (kt >> 5) & 1;
        if (kt + 32 < K) stage(kt + 32, cur ^ 1);

        const unsigned short* Ab = &As[cur][g * 1024];
        const unsigned short* Bb = &Bs[cur][g * (BN * 8)];
        i32x4 af[4], bf[NI];
#pragma unroll
        for (int mi = 0; mi < 4; ++mi)
            af[mi] = *reinterpret_cast<const i32x4*>(Ab + (wr * 64 + mi * 16 + r) * 8);
#pragma unroll
        for (int ni = 0; ni < NI; ++ni)
            bf[ni] = *reinterpret_cast<const i32x4*>(Bb + (wc * NW + ni * 16 + r) * 8);
#pragma unroll
        for (int mi = 0; mi < 4; ++mi)
#pragma unroll
            for (int ni = 0; ni < NI; ++ni)
                mfma_bf16(acc[mi][ni], af[mi], bf[ni]);

        __syncthreads();   // drains gl_lds (vmcnt) + ds reads; next buf ready
    }

#pragma unroll
    for (int ni = 0; ni < NI; ++ni) {
        const int n = col0 + wc * NW + ni * 16 + r;
        const float bv = bias[n];
#pragma unroll
        for (int mi = 0; mi < 4; ++mi) {
#pragma unroll
            for (int e = 0; e < 4; ++e) {
                const int m = row0 + wr * 64 + mi * 16 + g * 4 + e;
                const float val = acc[mi][ni][e] + bv;
                if constexpr (sizeof(OutT) == 2)
                    C[(size_t)m * N + n] = (OutT)f2bf(val);
                else
                    C[(size_t)m * N + n] = (OutT)val;
            }
        }
    }
}

// ---------------------------------------------------------------------------
// MFMA flash attention, 8 waves x 16 q-rows, Q tile 128, KV tile 64.
// r8-verified body (plain __expf softmax, unconditional rescale, no setprio)
// + T14 async V-staging: V-waves ds_write previously-loaded regs right after
// the barrier, then ISSUE next-next-tile loads before compute, so L2 latency
// hides under compute and drains at the end-of-tile barrier.
// ---------------------------------------------------------------------------
__global__ __launch_bounds__(512) void flash_attn_mfma(
    const unsigned short* __restrict__ qkv,  // [BS][3072]
    const float* __restrict__ mask,          // [B][S]
    unsigned short* __restrict__ out)        // [BS][1024]
{
    __shared__ alignas(16) unsigned short Klds[2][4096];  // [key][d^((key&7)<<3)]
    __shared__ alignas(16) unsigned short Vt[2][4096];    // [d][key^((d&7)<<3)]

    const int tid  = threadIdx.x;
    const int wave = tid >> 6;          // 0..7
    const int l    = tid & 63;
    const int g    = l >> 4;
    const int r    = l & 15;
    const int b    = blockIdx.z;
    const int h    = blockIdx.y;
    const int q0   = blockIdx.x * 128;
    const int qw   = q0 + wave * 16;    // this wave's 16 q-rows

    const size_t rs = 3 * (size_t)D_;
    const unsigned short* qb = qkv + (size_t)b * S_ * rs + (size_t)h * HD_;
    const unsigned short* kb = qb + D_;
    const unsigned short* vb = qb + 2 * D_;
    const float* mrow = mask + (size_t)b * S_;

    // Q fragments: q = qw + r, d = ks*32 + g*8 + j
    i32x4 qf[2];
#pragma unroll
    for (int ks = 0; ks < 2; ++ks)
        qf[ks] = *reinterpret_cast<const i32x4*>(
            qb + (size_t)(qw + r) * rs + ks * 32 + g * 8);

    // K staging (waves 0-3, r4 mapping): keys wave*16 + t*8 + (l>>3)
    const int kkey = (wave & 3) * 16 + (l >> 3);
    const int kuni = ((l & 7) ^ (l >> 3)) * 8;
    // V staging (waves 4-7, r4 mapping with w' = wave-4)
    const int vkey = (wave & 3) * 16 + (l >> 2);
    const int vpart = l & 3;

    ushort4 vr[4];   // in-flight V registers (next tile's data)
    auto vload = [&](int kt) {
#pragma unroll
        for (int p = 0; p < 4; ++p)
            vr[p] = *reinterpret_cast<const ushort4*>(
                vb + (size_t)(kt + vkey) * rs + p * 16 + vpart * 4);
    };
    auto vwrite = [&](int buf) {
#pragma unroll
        for (int p = 0; p < 4; ++p) {
            const int d0 = p * 16 + vpart * 4;
            Vt[buf][(d0 + 0) * 64 + (vkey ^ (((d0 + 0) & 7) << 3))] = vr[p].x;
            Vt[buf][(d0 + 1) * 64 + (vkey ^ (((d0 + 1) & 7) << 3))] = vr[p].y;
            Vt[buf][(d0 + 2) * 64 + (vkey ^ (((d0 + 2) & 7) << 3))] = vr[p].z;
            Vt[buf][(d0 + 3) * 64 + (vkey ^ (((d0 + 3) & 7) << 3))] = vr[p].w;
        }
    };

    f32x4 acc[4];     // O^T: d = mi*16 + g*4 + e, q = r
    float m_i = -1e30f, l_i = 0.f;
#pragma unroll
    for (int mi = 0; mi < 4; ++mi) acc[mi] = (f32x4)0.f;

    // prologue: tile 0 into buf 0; V regs for tile 1 in flight
    if (wave < 4) {
        gl_lds16(kb + (size_t)(0 + kkey) * rs + kuni,     &Klds[0][(wave & 3) * 1024]);
        gl_lds16(kb + (size_t)(0 + kkey + 8) * rs + kuni, &Klds[0][(wave & 3) * 1024 + 512]);
    } else {
        vload(0);
        vwrite(0);        // waits vmcnt internally (prologue only)
        vload(64);        // tile 1 regs, drains at first barrier
    }
    __syncthreads();

    for (int kt = 0; kt < S_; kt += 64) {
        const int cur = (kt >> 6) & 1;
        if (wave < 4) {
            if (kt + 64 < S_) {
                gl_lds16(kb + (size_t)(kt + 64 + kkey) * rs + kuni,
                         &Klds[cur ^ 1][(wave & 3) * 1024]);
                gl_lds16(kb + (size_t)(kt + 64 + kkey + 8) * rs + kuni,
                         &Klds[cur ^ 1][(wave & 3) * 1024 + 512]);
            }
        } else {
            if (kt + 64 < S_) vwrite(cur ^ 1);   // vr = tile t+1 (loads drained)
            if (kt + 128 < S_) vload(kt + 128);  // issue t+2; hides under compute
        }

        const unsigned short* Kb = Klds[cur];
        const unsigned short* Vb = Vt[cur];

        // --- S^T = K · Q^T : s[mi], key = mi*16 + g*4 + e, q = r ---
        f32x4 s[4];
#pragma unroll
        for (int mi = 0; mi < 4; ++mi) s[mi] = (f32x4)0.f;
#pragma unroll
        for (int ks = 0; ks < 2; ++ks)
#pragma unroll
            for (int mi = 0; mi < 4; ++mi) {
                const i32x4 kf = *reinterpret_cast<const i32x4*>(
                    Kb + (mi * 16 + r) * 64 + ((ks * 32 + g * 8) ^ ((r & 7) << 3)));
                mfma_bf16(s[mi], kf, qf[ks]);
            }

        // --- scale + additive mask (key-indexed) ---
#pragma unroll
        for (int mi = 0; mi < 4; ++mi) {
            const float4 mk = *reinterpret_cast<const float4*>(
                mrow + kt + mi * 16 + g * 4);
            s[mi][0] = s[mi][0] * 0.125f + mk.x;
            s[mi][1] = s[mi][1] * 0.125f + mk.y;
            s[mi][2] = s[mi][2] * 0.125f + mk.z;
            s[mi][3] = s[mi][3] * 0.125f + mk.w;
        }

        // --- online softmax + pack P to bf16 ---
        float tmax = -1e30f;
#pragma unroll
        for (int mi = 0; mi < 4; ++mi)
#pragma unroll
            for (int e = 0; e < 4; ++e)
                tmax = fmaxf(tmax, s[mi][e]);
        tmax = fmaxf(tmax, __shfl_xor(tmax, 16));
        tmax = fmaxf(tmax, __shfl_xor(tmax, 32));
        const float mnew = fmaxf(m_i, tmax);
        const float corr = __expf(m_i - mnew);
        m_i = mnew;

        unsigned int pk[4][2];   // [mi][wl]: keys (mi*16 + g*4 + 2wl, +1)
        float ls = 0.f;
#pragma unroll
        for (int mi = 0; mi < 4; ++mi) {
            const float p0 = __expf(s[mi][0] - mnew);
            const float p1 = __expf(s[mi][1] - mnew);
            const float p2 = __expf(s[mi][2] - mnew);
            const float p3 = __expf(s[mi][3] - mnew);
            ls += (p0 + p1) + (p2 + p3);
            pk[mi][0] = cvtpk_bf16(p0, p1);
            pk[mi][1] = cvtpk_bf16(p2, p3);
        }
        l_i = l_i * corr + ls;   // lane-partial over g; reduced at end
#pragma unroll
        for (int mi = 0; mi < 4; ++mi) acc[mi] *= corr;

        // --- PV: O^T += V^T · P^T ---
#pragma unroll
        for (int ks = 0; ks < 2; ++ks) {
            i32x4 pf;   // word w = keys ks*32 + g*8 + 2w, +1 of q-row r
#pragma unroll
            for (int w = 0; w < 4; ++w) {
                const int src = (((g & 1) * 2 + (w >> 1)) << 4) + r;
                const unsigned int vA = __shfl(pk[2 * ks + 0][w & 1], src);
                const unsigned int vB = __shfl(pk[2 * ks + 1][w & 1], src);
                pf[w] = (int)((g >> 1) ? vB : vA);
            }
#pragma unroll
            for (int mi = 0; mi < 4; ++mi) {
                const i32x4 vf = *reinterpret_cast<const i32x4*>(
                    Vb + (mi * 16 + r) * 64 + ((ks * 32 + g * 8) ^ ((r & 7) << 3)));
                mfma_bf16(acc[mi], vf, pf);
            }
        }

        __syncthreads();   // drains stage's vmcnt/lgkm; next buf ready
    }

    // --- epilogue: reduce l over g-lanes, divide, store bf16 ---
    float lf = l_i;
    lf += __shfl_xor(lf, 16);
    lf += __shfl_xor(lf, 32);
    const float inv = 1.0f / lf;
    const size_t token = (size_t)b * S_ + qw + r;
#pragma unroll
    for (int mi = 0; mi < 4; ++mi) {
        const f32x4 v = acc[mi] * inv;
        uint2 w;
        w.x = cvtpk_bf16(v[0], v[1]);
        w.y = cvtpk_bf16(v[2], v[3]);
        *reinterpret_cast<uint2*>(
            out + token * D_ + h * HD_ + mi * 16 + g * 4) = w;
    }
}

// ---------------------------------------------------------------------------
extern "C" void kernel_launch(void* const* d_in, const int* in_sizes, int n_in,
                              void* d_out, int out_size, void* d_ws, size_t ws_size,
                              hipStream_t stream)
{
    const float* x      = (const float*)d_in[0];   // [2,2048,1024]
    const float* amask  = (const float*)d_in[1];   // [2,2048]
    const float* w_attn = (const float*)d_in[2];   // [1024,3072]
    const float* b_attn = (const float*)d_in[3];   // [3072]
    const float* w_proj = (const float*)d_in[4];   // [1024,1024]
    const float* b_proj = (const float*)d_in[5];   // [1024]
    float* out = (float*)d_out;                    // [2,2048,1024] fp32

    unsigned short* qkvb  = (unsigned short*)d_ws;                  // [4096][3072] bf16
    unsigned short* attnb = qkvb  + (size_t)BS_ * 3 * D_;           // [4096][1024] bf16
    unsigned short* xb    = attnb + (size_t)BS_ * D_;               // [4096][1024] bf16
    unsigned short* wat   = xb    + (size_t)BS_ * D_;               // [3072][1024] bf16
    unsigned short* wpt   = wat   + (size_t)3 * D_ * D_;            // [1024][1024] bf16

    convert_f32_bf16<<<(BS_ * D_) / 2048, 256, 0, stream>>>(x, xb, BS_ * D_);
    transpose_cvt<<<dim3(3 * D_ / 32, D_ / 32), 256, 0, stream>>>(w_attn, wat, D_, 3 * D_);
    transpose_cvt<<<dim3(D_ / 32, D_ / 32), 256, 0, stream>>>(w_proj, wpt, D_, D_);

    // 1) QKV projection (bf16 MFMA) -> bf16 qkv
    gemm_bt_bf16<unsigned short, 128><<<dim3(3 * D_ / 128, BS_ / 128), 256, 0, stream>>>(
        xb, wat, b_attn, qkvb, BS_, 3 * D_, D_);

    // 2) MFMA flash attention -> bf16
    flash_attn_mfma<<<dim3(S_ / 128, H_, B_), 512, 0, stream>>>(qkvb, amask, attnb);

    // 3) output projection (bf16 MFMA, BN=64 -> 512 blocks = 2/CU) -> fp32
    gemm_bt_bf16<float, 64><<<dim3(D_ / 64, BS_ / 128), 256, 0, stream>>>(
        attnb, wpt, b_proj, out, BS_, D_, D_);
}